// Round 1
// baseline (722.922 us; speedup 1.0000x reference)
//
#include <hip/hip_runtime.h>
#include <hip/hip_bf16.h>

#define HDIM 512
#define TILE 64
#define TPB 512

typedef __attribute__((ext_vector_type(8))) short short8;
typedef __attribute__((ext_vector_type(4))) float f32x4;

__device__ __forceinline__ unsigned short f2bf(float x) {
  unsigned u = __float_as_uint(x);
  u = (u + 0x7fffu + ((u >> 16) & 1u)) >> 16;   // RNE
  return (unsigned short)u;
}
__device__ __forceinline__ float bf2f(unsigned short h) {
  return __uint_as_float(((unsigned)h) << 16);
}
// XOR-swizzled ushort index into a [row][col] bf16 tile, row stride 512 elems.
__device__ __forceinline__ int swz(int row, int col) {
  return (((row << 10) + (col << 1)) ^ ((row & 7) << 4)) >> 1;
}

// Pre-convert W2 (512x512 f32 row-major, [k][n]) into bf16 MFMA-fragment-major
// layouts: fwd B[k][n] and bwd B'[k'][n'] = W2[n'][k'].
// Fragment (nb, kb): lane l, elem j supplies B[kb*32 + (l>>4)*8 + j][nb*16 + (l&15)].
__global__ void prep_weights(const float* __restrict__ pW2, const float* __restrict__ tW2,
                             unsigned short* __restrict__ pWf, unsigned short* __restrict__ pWb,
                             unsigned short* __restrict__ tWf, unsigned short* __restrict__ tWb) {
  int i = blockIdx.x * blockDim.x + threadIdx.x;
  if (i >= HDIM * HDIM) return;
  int j  = i & 7;
  int l  = (i >> 3) & 63;
  int kb = (i >> 9) & 15;
  int nb = i >> 13;
  int kpos = kb * 32 + ((l >> 4) << 3) + j;
  int npos = nb * 16 + (l & 15);
  pWf[i] = f2bf(pW2[kpos * HDIM + npos]);
  pWb[i] = f2bf(pW2[npos * HDIM + kpos]);
  tWf[i] = f2bf(tW2[kpos * HDIM + npos]);
  tWb[i] = f2bf(tW2[npos * HDIM + kpos]);
}

template <int ARITY>
__global__ void __launch_bounds__(TPB, 2)
energy_kernel(const float* __restrict__ x, const float* __restrict__ sigp,
              const int* __restrict__ edges, int Etot,
              const float* __restrict__ W1, const float* __restrict__ b1,
              const unsigned short* __restrict__ Wf, const unsigned short* __restrict__ Wb,
              const float* __restrict__ b2, const float* __restrict__ w3,
              const float* __restrict__ b3p, float* __restrict__ out) {
  constexpr int IN = ARITY * 2 + ARITY;   // arity*dim + arity
  constexpr int GD = ARITY * 2;           // grad components per edge
  __shared__ __align__(16) unsigned short bufA[TILE * HDIM];  // h1 -> dz2 -> dz1 (64 KB)
  __shared__ __align__(16) unsigned short W1s[IN * HDIM];     // bf16 W1
  __shared__ float h0s[TILE][16];
  __shared__ int   idxs[TILE * ARITY];
  __shared__ float blockE;

  const int tid  = threadIdx.x;
  const int lane = tid & 63;
  const int w    = tid >> 6;
  const int tile0 = blockIdx.x * TILE;
  const int vcnt  = min(TILE, Etot - tile0);
  const float sigma = sigp[0];

  if (tid == 0) blockE = 0.f;
  // ---- phase 0: indices + gather x -> h0 ----
  if (tid < TILE * ARITY) {
    int e = tid / ARITY;
    idxs[tid] = (e < vcnt) ? edges[(size_t)tile0 * ARITY + tid] : 0;
  }
  __syncthreads();
  if (tid < TILE) {
    if (tid < vcnt) {
#pragma unroll
      for (int o = 0; o < ARITY; ++o) {
        int id = idxs[tid * ARITY + o];
        h0s[tid][o * 2 + 0] = x[id * 2 + 0];
        h0s[tid][o * 2 + 1] = x[id * 2 + 1];
        h0s[tid][ARITY * 2 + o] = sigma;
      }
    } else {
#pragma unroll
      for (int k = 0; k < 16; ++k) h0s[tid][k] = 0.f;
    }
  }
  __syncthreads();

  // ---- phase 1: layer 1 (fp32 VALU), thread t owns hidden unit n = t ----
  {
    const int n = tid;
    float w1c[IN];
    const float b1n = b1[n];
#pragma unroll
    for (int k = 0; k < IN; ++k) {
      w1c[k] = W1[k * HDIM + n];
      W1s[k * HDIM + n] = f2bf(w1c[k]);
    }
    for (int e = 0; e < TILE; ++e) {
      float z = b1n;
#pragma unroll
      for (int k = 0; k < IN; ++k) z += h0s[e][k] * w1c[k];
      float s = 1.f / (1.f + __expf(-z));
      float hv = (e < vcnt) ? z * s : 0.f;
      bufA[swz(e, n)] = f2bf(hv);
    }
  }
  __syncthreads();

  // per-wave output-column constants (wave w owns cols [w*64, w*64+64))
  const int n0 = w * 64;
  int coln[4]; float b2v[4], w3v[4];
#pragma unroll
  for (int nf = 0; nf < 4; ++nf) {
    coln[nf] = n0 + nf * 16 + (lane & 15);
    b2v[nf] = b2[coln[nf]];
    w3v[nf] = w3[coln[nf]];
  }

  // ---- phase 2: forward GEMM  z2 = h1 @ W2 ----
  f32x4 acc[4][4];
#pragma unroll
  for (int mf = 0; mf < 4; ++mf)
#pragma unroll
    for (int nf = 0; nf < 4; ++nf)
      acc[mf][nf] = (f32x4){0.f, 0.f, 0.f, 0.f};

#pragma unroll 4
  for (int kk = 0; kk < 16; ++kk) {
    short8 a[4];
#pragma unroll
    for (int mf = 0; mf < 4; ++mf)
      a[mf] = *(const short8*)&bufA[swz(mf * 16 + (lane & 15), kk * 32 + ((lane >> 4) << 3))];
#pragma unroll
    for (int nf = 0; nf < 4; ++nf) {
      short8 bfr = *(const short8*)(Wf + ((((w * 4 + nf) * 16 + kk) * 64 + lane) << 3));
#pragma unroll
      for (int mf = 0; mf < 4; ++mf)
        acc[mf][nf] = __builtin_amdgcn_mfma_f32_16x16x32_bf16(a[mf], bfr, acc[mf][nf], 0, 0, 0);
    }
  }

  // ---- epilogue fwd: energy head + dz2 = w3 * silu'(z2) (kept in acc) ----
  float epart = 0.f;
#pragma unroll
  for (int mf = 0; mf < 4; ++mf) {
#pragma unroll
    for (int r = 0; r < 4; ++r) {
      int row = mf * 16 + ((lane >> 4) << 2) + r;
      bool val = row < vcnt;
#pragma unroll
      for (int nf = 0; nf < 4; ++nf) {
        float z = acc[mf][nf][r] + b2v[nf];
        float s = 1.f / (1.f + __expf(-z));
        float h2 = z * s;
        float sp = s * (1.f + z * (1.f - s));
        epart += val ? h2 * w3v[nf] : 0.f;
        acc[mf][nf][r] = val ? w3v[nf] * sp : 0.f;
      }
    }
  }
#pragma unroll
  for (int off = 32; off > 0; off >>= 1) epart += __shfl_down(epart, off, 64);
  if (lane == 0) atomicAdd(&blockE, epart);

  __syncthreads();  // everyone done reading h1
#pragma unroll
  for (int mf = 0; mf < 4; ++mf)
#pragma unroll
    for (int nf = 0; nf < 4; ++nf)
#pragma unroll
      for (int r = 0; r < 4; ++r)
        bufA[swz(mf * 16 + ((lane >> 4) << 2) + r, coln[nf])] = f2bf(acc[mf][nf][r]);
  __syncthreads();

  if (tid == 0) atomicAdd(out, blockE + (float)vcnt * b3p[0]);

  // ---- phase 3: backward GEMM  dH1 = dz2 @ W2^T ----
#pragma unroll
  for (int mf = 0; mf < 4; ++mf)
#pragma unroll
    for (int nf = 0; nf < 4; ++nf)
      acc[mf][nf] = (f32x4){0.f, 0.f, 0.f, 0.f};

#pragma unroll 4
  for (int kk = 0; kk < 16; ++kk) {
    short8 a[4];
#pragma unroll
    for (int mf = 0; mf < 4; ++mf)
      a[mf] = *(const short8*)&bufA[swz(mf * 16 + (lane & 15), kk * 32 + ((lane >> 4) << 3))];
#pragma unroll
    for (int nf = 0; nf < 4; ++nf) {
      short8 bfr = *(const short8*)(Wb + ((((w * 4 + nf) * 16 + kk) * 64 + lane) << 3));
#pragma unroll
      for (int mf = 0; mf < 4; ++mf)
        acc[mf][nf] = __builtin_amdgcn_mfma_f32_16x16x32_bf16(a[mf], bfr, acc[mf][nf], 0, 0, 0);
    }
  }

  // ---- phase 4: dz1 = dH1 * silu'(z1), z1 recomputed from h0 ----
  {
    float b1v[4], w1v[4][IN];
#pragma unroll
    for (int nf = 0; nf < 4; ++nf) {
      b1v[nf] = b1[coln[nf]];
#pragma unroll
      for (int k = 0; k < IN; ++k) w1v[nf][k] = bf2f(W1s[k * HDIM + coln[nf]]);
    }
#pragma unroll
    for (int mf = 0; mf < 4; ++mf) {
#pragma unroll
      for (int r = 0; r < 4; ++r) {
        int row = mf * 16 + ((lane >> 4) << 2) + r;
#pragma unroll
        for (int nf = 0; nf < 4; ++nf) {
          float z = b1v[nf];
#pragma unroll
          for (int k = 0; k < IN; ++k) z += h0s[row][k] * w1v[nf][k];
          float s = 1.f / (1.f + __expf(-z));
          float sp = s * (1.f + z * (1.f - s));
          acc[mf][nf][r] = acc[mf][nf][r] * sp;
        }
      }
    }
  }
  __syncthreads();  // everyone done reading dz2
#pragma unroll
  for (int mf = 0; mf < 4; ++mf)
#pragma unroll
    for (int nf = 0; nf < 4; ++nf)
#pragma unroll
      for (int r = 0; r < 4; ++r)
        bufA[swz(mf * 16 + ((lane >> 4) << 2) + r, coln[nf])] = f2bf(acc[mf][nf][r]);
  __syncthreads();

  // ---- phase 5: dh0[e][k] = sum_n dz1[e][n] * W1[k][n]; scatter to grad ----
  {
    int e = tid >> 3;
    int k = tid & 7;
    if (k < GD) {
      float ssum = 0.f;
      for (int c = 0; c < HDIM / 8; ++c) {
        short8 a8 = *(const short8*)&bufA[swz(e, c * 8)];
        short8 w8 = *(const short8*)&W1s[k * HDIM + c * 8];
#pragma unroll
        for (int j = 0; j < 8; ++j)
          ssum += bf2f((unsigned short)a8[j]) * bf2f((unsigned short)w8[j]);
      }
      if (e < vcnt) {
        int obj = k >> 1, d = k & 1;
        atomicAdd(&out[1 + idxs[e * ARITY + obj] * 2 + d], ssum);
      }
    }
  }
}

extern "C" void kernel_launch(void* const* d_in, const int* in_sizes, int n_in,
                              void* d_out, int out_size, void* d_ws, size_t ws_size,
                              hipStream_t stream) {
  const float* x    = (const float*)d_in[0];
  const float* sig  = (const float*)d_in[1];
  const int*   ep   = (const int*)d_in[2];
  const int*   et   = (const int*)d_in[3];
  const float* pW1  = (const float*)d_in[4];
  const float* pb1  = (const float*)d_in[5];
  const float* pW2  = (const float*)d_in[6];
  const float* pb2  = (const float*)d_in[7];
  const float* pW3  = (const float*)d_in[8];
  const float* pb3  = (const float*)d_in[9];
  const float* tW1  = (const float*)d_in[10];
  const float* tb1  = (const float*)d_in[11];
  const float* tW2  = (const float*)d_in[12];
  const float* tb2  = (const float*)d_in[13];
  const float* tW3  = (const float*)d_in[14];
  const float* tb3  = (const float*)d_in[15];
  const int E2 = in_sizes[2] / 2;
  const int E3 = in_sizes[3] / 3;
  float* out = (float*)d_out;

  unsigned short* pWf = (unsigned short*)d_ws;
  unsigned short* pWb = pWf + HDIM * HDIM;
  unsigned short* tWf = pWb + HDIM * HDIM;
  unsigned short* tWb = tWf + HDIM * HDIM;

  hipMemsetAsync(d_out, 0, (size_t)out_size * sizeof(float), stream);
  prep_weights<<<(HDIM * HDIM + 255) / 256, 256, 0, stream>>>(pW2, tW2, pWf, pWb, tWf, tWb);
  energy_kernel<2><<<(E2 + TILE - 1) / TILE, TPB, 0, stream>>>(
      x, sig, ep, E2, pW1, pb1, pWf, pWb, pb2, pW3, pb3, out);
  energy_kernel<3><<<(E3 + TILE - 1) / TILE, TPB, 0, stream>>>(
      x, sig, et, E3, tW1, tb1, tWf, tWb, tb2, tW3, tb3, out);
}